// Round 1
// baseline (9355.556 us; speedup 1.0000x reference)
//
#include <hip/hip_runtime.h>
#include <hip/hip_bf16.h>
#include <math.h>

// Problem constants: T=128, B=32, D=512, H=512, N=64, A=32, TAU=1
#define NTHR 512
#define GRID_P 216          // persistent grid: 18 col-groups x 12 K-splits

// ---- workspace layout (float offsets). Barrier ints live in first 128B. ----
#define OFF_HTX   32                         // hTx: [576][32] = [h rows | lu rows]
#define SZ_HTX    (576*32)
#define OFF_HNEW  (OFF_HTX + SZ_HTX)         // hnew_part: [32][64][512]  (mem slot -> h@fc2_A)
#define SZ_HNEW   (32*64*512)
#define OFF_WHH   (OFF_HNEW + SZ_HNEW)       // whh_part: [32][64][1536] ((h@fc2_A)@W_hh)
#define SZ_WHH    (32*64*1536)
#define OFF_USAGE (OFF_WHH + SZ_WHH)         // usage: [32][64]
#define OFF_JSTAR (OFF_USAGE + 2048)         // jstar: 32 ints
#define OFF_C0    (OFF_JSTAR + 32)           // c0 = fc2_b@W_hh + bias_hh : [1536]
#define OFF_WCAT  (OFF_C0 + 1536)            // Wcat: [576][4608]
#define SZ_WCAT   (576*4608)
#define OFF_PART  (OFF_WCAT + SZ_WCAT)       // split-K partials: [12][32][4608]
#define SZ_PART   (12*32*4608)
#define OFF_P1    (OFF_PART + SZ_PART)       // P1 = x@W_ih + bias_ih : [4096][1536]
#define SZ_P1     (4096*1536)
#define OFF_P2    (OFF_P1 + SZ_P1)           // P2 = x@W_im : [4096][512]
#define SZ_P2     (4096*512)
#define OFF_HS    (OFF_P2 + SZ_P2)           // hs: [4096][512]
// total = OFF_HS + 4096*512 = 19,125,824 floats ~ 76.5 MB

// ---------------------------------------------------------------------------
// Generic tiled fp32 GEMM: C[M,N] = A[M,K]@B[K,N] (+bias). BM=128 BN=64 BK=16,
// 256 threads, 8x4 per thread. All dims must divide tiles (they do here).
// ---------------------------------------------------------------------------
__global__ __launch_bounds__(256) void gemm_f32(
    const float* __restrict__ A, const float* __restrict__ B,
    const float* __restrict__ bias, float* __restrict__ C,
    int M, int N, int K, int lda, int ldb, int ldc)
{
  __shared__ float As[16][132];   // [k][m], padded
  __shared__ float Bs[16][64];    // [k][n]
  const int bm = blockIdx.x * 128, bn = blockIdx.y * 64;
  const int tid = threadIdx.x;
  const int tx = tid & 15, ty = tid >> 4;   // tx: n-quad, ty: m-octet
  float acc[8][4];
  #pragma unroll
  for (int i = 0; i < 8; ++i)
    #pragma unroll
    for (int j = 0; j < 4; ++j) acc[i][j] = 0.f;

  for (int kt = 0; kt < K; kt += 16) {
    #pragma unroll
    for (int i = 0; i < 2; ++i) {           // A tile: 128x16 = 512 float4
      int li = tid + i*256;
      int r = li >> 2, q = li & 3;
      float4 a4 = *(const float4*)(A + (size_t)(bm + r)*lda + kt + q*4);
      As[q*4+0][r] = a4.x; As[q*4+1][r] = a4.y;
      As[q*4+2][r] = a4.z; As[q*4+3][r] = a4.w;
    }
    {                                       // B tile: 16x64 = 256 float4
      int k = tid >> 4, nq = tid & 15;
      *(float4*)(&Bs[k][nq*4]) = *(const float4*)(B + (size_t)(kt + k)*ldb + bn + nq*4);
    }
    __syncthreads();
    #pragma unroll
    for (int kk = 0; kk < 16; ++kk) {
      float av[8], bv[4];
      *(float4*)(av)   = *(const float4*)(&As[kk][ty*8]);
      *(float4*)(av+4) = *(const float4*)(&As[kk][ty*8+4]);
      *(float4*)(bv)   = *(const float4*)(&Bs[kk][tx*4]);
      #pragma unroll
      for (int i = 0; i < 8; ++i)
        #pragma unroll
        for (int j = 0; j < 4; ++j) acc[i][j] += av[i]*bv[j];
    }
    __syncthreads();
  }
  #pragma unroll
  for (int i = 0; i < 8; ++i) {
    int m = bm + ty*8 + i;
    #pragma unroll
    for (int j = 0; j < 4; ++j) {
      int n = bn + tx*4 + j;
      float v = acc[i][j];
      if (bias) v += bias[n];
      C[(size_t)m*ldc + n] = v;
    }
  }
}

// ---------------------------------------------------------------------------
// Setup: build Wcat static parts, usage init, c0, jstar.
// Wcat cols: [0:512)=W_hm  [512:1024)=fc2_A  [1024:1536)=fc2_B
//           [1536:3072)=M_A (by GEMM)  [3072:4608)=M_B (by GEMM)
// Wcat rows 512:576 = [W_um | zeros]  (hx rows 512:576 = last_use)
// ---------------------------------------------------------------------------
__global__ __launch_bounds__(512) void setup_kernel(
    const float* __restrict__ W_hm, const float* __restrict__ fc2_w,
    const float* __restrict__ W_um, const float* __restrict__ W_hh,
    const float* __restrict__ bias, const float* __restrict__ fc2_b,
    float* __restrict__ Wcat, float* __restrict__ usage,
    float* __restrict__ c0, int* __restrict__ jstar)
{
  const int idx = blockIdx.x * 512 + threadIdx.x;
  if (idx < 512*1536) {                       // seg0: rows 0:512, cols 0:1536
    int k = idx / 1536, c = idx % 1536;
    float v;
    if (c < 512)       v = W_hm[k*512 + c];
    else if (c < 1024) v = fc2_w[k*512 + (c-512)];
    else               v = fc2_w[(512+k)*512 + (c-1024)];
    Wcat[(size_t)k*4608 + c] = v;
    return;
  }
  int i = idx - 512*1536;
  if (i < 64*4608) {                          // seg1: rows 512:576, all cols
    int k2 = i / 4608, c = i % 4608;
    Wcat[(size_t)(512+k2)*4608 + c] = (c < 512) ? W_um[k2*512 + c] : 0.f;
    return;
  }
  i -= 64*4608;
  if (i < 2048) { usage[i] = -99999.0f; return; }   // seg2
  i -= 2048;
  if (i < 32) { jstar[i] = 0; return; }             // seg3
  i -= 32;
  if (i < 1536) {                                   // seg4: c0
    float s = bias[1536 + i];                       // bias_hh
    for (int m = 0; m < 512; ++m) s += fc2_b[m] * W_hh[m*1536 + i];
    c0[i] = s;
  }
}

// ---------------------------------------------------------------------------
// Monotonic sense-free grid barrier (agent scope). Grid must be co-resident:
// 216 blocks x 512 thr, ~43KB LDS, 1 block/CU on a 256-CU device -> safe.
// ---------------------------------------------------------------------------
__device__ __forceinline__ void gbar(int* cnt, int* flag, int id)
{
  __syncthreads();
  if (threadIdx.x == 0) {
    int old = __hip_atomic_fetch_add(cnt, 1, __ATOMIC_RELEASE, __HIP_MEMORY_SCOPE_AGENT);
    if (old == id * GRID_P - 1) {
      __hip_atomic_store(flag, id, __ATOMIC_RELEASE, __HIP_MEMORY_SCOPE_AGENT);
    } else {
      while (__hip_atomic_load(flag, __ATOMIC_RELAXED, __HIP_MEMORY_SCOPE_AGENT) < id)
        __builtin_amdgcn_s_sleep(2);
    }
    __threadfence();   // agent-scope acquire: invalidate stale L1/L2 lines
  }
  __syncthreads();
}

// ---------------------------------------------------------------------------
// Persistent scan kernel: 128 steps x { Phase A (split-K GEMM), barrier,
// Phase BC (argmax + elementwise), barrier }.
// ---------------------------------------------------------------------------
__global__ __launch_bounds__(NTHR, 2) void persist_kernel(
    const float* __restrict__ P1, const float* __restrict__ P2,
    const float* __restrict__ Wcat, float* __restrict__ partial,
    float* __restrict__ hTx, float* __restrict__ hnew_part,
    float* __restrict__ whh_part, float* __restrict__ usage,
    int* __restrict__ jstar, const float* __restrict__ c0,
    const float* __restrict__ fc1_w, const float* __restrict__ fc1_b,
    const float* __restrict__ fc2_b, const float* __restrict__ u_noise,
    const int* __restrict__ length, float* __restrict__ hs,
    int* __restrict__ bar)
{
  __shared__ float hxs[48*32];     // staged hx rows for this K-split
  __shared__ float red[32*256];    // K-half reduction
  __shared__ float th_s[512];
  __shared__ float lg[512];
  __shared__ float lsc[64];
  __shared__ int jj_s, ss_s;

  const int bid = blockIdx.x;
  const int tid = threadIdx.x;
  int* cnt  = bar;
  int* flag = bar + 1;

  const int cg = bid / 12;          // 0..17: 256-column group
  const int ks = bid % 12;          // 0..11: 48-row K split
  const int c  = tid & 255;
  const int kh = tid >> 8;          // K half (24 rows each)
  const int col = cg*256 + c;

  for (int t = 0; t < 128; ++t) {
    // ---------------- PHASE A: partial[ks] = hx[ksplit] @ Wcat[:, col] -----
    for (int i = tid; i < 48*32; i += NTHR) hxs[i] = hTx[ks*48*32 + i];
    __syncthreads();
    {
      float acc[32];
      #pragma unroll
      for (int b = 0; b < 32; ++b) acc[b] = 0.f;
      const float* wp = Wcat + (size_t)(ks*48 + kh*24)*4608 + col;
      const float* hb = hxs + kh*24*32;
      float w = wp[0];
      for (int k = 0; k < 24; ++k) {
        float wn = (k < 23) ? wp[(size_t)(k+1)*4608] : 0.f;
        const float* h4p = hb + k*32;
        #pragma unroll
        for (int q = 0; q < 8; ++q) {
          float4 h4 = *(const float4*)(h4p + q*4);
          acc[q*4+0] += w*h4.x; acc[q*4+1] += w*h4.y;
          acc[q*4+2] += w*h4.z; acc[q*4+3] += w*h4.w;
        }
        w = wn;
      }
      if (kh == 1) {
        #pragma unroll
        for (int b = 0; b < 32; ++b) red[b*256 + c] = acc[b];
      }
      __syncthreads();
      if (kh == 0) {
        float* pp = partial + (size_t)(ks*32)*4608 + col;
        #pragma unroll
        for (int b = 0; b < 32; ++b) pp[(size_t)b*4608] = acc[b] + red[b*256 + c];
      }
    }
    gbar(cnt, flag, 2*t + 1);

    // ---------------- PHASE BC: block b<32 handles batch b -----------------
    if (bid < 32) {
      const int b = bid;
      const int t32b = t*32 + b;
      // th = tanh(P2 + sum_s partial[:, 0:512])
      {
        float pre = P2[(size_t)t32b*512 + tid];
        #pragma unroll
        for (int s = 0; s < 12; ++s) pre += partial[(size_t)(s*32+b)*4608 + tid];
        th_s[tid] = tanhf(pre);
      }
      __syncthreads();
      // logits partial dots: tid -> (n = tid&63, kg = tid>>6), K chunk of 64
      {
        int n = tid & 63, kg = tid >> 6;
        float sum = 0.f;
        const float* fw = fc1_w + (size_t)kg*64*64 + n;
        #pragma unroll 8
        for (int k = 0; k < 64; ++k) sum += th_s[kg*64 + k] * fw[(size_t)k*64];
        lg[tid] = sum;
      }
      __syncthreads();
      if (tid < 64) {
        float l = fc1_b[tid];
        #pragma unroll
        for (int kg = 0; kg < 8; ++kg) l += lg[kg*64 + tid];
        float u = u_noise[(size_t)t32b*64 + tid];
        l += -logf(1e-20f - logf(1e-20f + u));     // Gumbel
        lsc[tid] = l;
      }
      __syncthreads();
      if (tid == 0) {
        int jj = 0; float best = lsc[0];
        for (int n2 = 1; n2 < 64; ++n2)
          if (lsc[n2] > best) { best = lsc[n2]; jj = n2; }   // first-max wins
        jj_s = jj;
        ss_s = (t < 64) ? t : jstar[b];   // write slot (mem write precedes read)
        jstar[b] = jj;
      }
      __syncthreads();
      const int jj = jj_s, ss = ss_s;
      {
        const int j = tid;    // 0..511
        float vA=0.f, vB=0.f, vAW0=0.f, vAW1=0.f, vAW2=0.f, vBW0=0.f, vBW1=0.f, vBW2=0.f;
        #pragma unroll
        for (int s = 0; s < 12; ++s) {
          const float* pr = partial + (size_t)(s*32+b)*4608;
          vA   += pr[ 512 + j]; vB   += pr[1024 + j];
          vAW0 += pr[1536 + j]; vAW1 += pr[2048 + j]; vAW2 += pr[2560 + j];
          vBW0 += pr[3072 + j]; vBW1 += pr[3584 + j]; vBW2 += pr[4096 + j];
        }
        float hnp, w0, w1, w2;
        if (jj == ss) { hnp = vA; w0 = vAW0; w1 = vAW1; w2 = vAW2; }  // reads just-written slot
        else {
          hnp = hnew_part[(size_t)(b*64 + jj)*512 + j];
          const float* wpp = whh_part + (size_t)(b*64 + jj)*1536;
          w0 = wpp[j]; w1 = wpp[512 + j]; w2 = wpp[1024 + j];
        }
        float h_new = hnp + vB + fc2_b[j];
        float wh_r = w0 + vBW0 + c0[j];
        float wh_z = w1 + vBW1 + c0[512 + j];
        float wh_n = w2 + vBW2 + c0[1024 + j];
        const float* p1 = P1 + (size_t)t32b*1536;
        float r = 1.f / (1.f + expf(-(p1[j]        + wh_r)));
        float z = 1.f / (1.f + expf(-(p1[512 + j]  + wh_z)));
        float nn = tanhf(p1[1024 + j] + r*wh_n);
        float h1 = (1.f - z)*nn + z*h_new;
        float hprev = hTx[j*32 + b];
        if (t >= length[b]) h1 = hprev;                    // length mask
        hTx[j*32 + b] = h1;
        hs[(size_t)t32b*512 + j] = h1;
        hnew_part[(size_t)(b*64 + ss)*512 + j] = vA;       // mem slot write cache
        float* wps = whh_part + (size_t)(b*64 + ss)*1536;
        wps[j] = vAW0; wps[512 + j] = vAW1; wps[1024 + j] = vAW2;
      }
      if (tid < 64) {
        float un = (usage[b*64 + tid] - 1.f) * (tid == jj ? 0.f : 1.f);
        usage[b*64 + tid] = un;
        hTx[(512 + tid)*32 + b] = 1.f / (1.f + expf(-un)); // lu for next step
      }
    }
    gbar(cnt, flag, 2*t + 2);
  }
}

// ---------------------------------------------------------------------------
// out[4096,32] = hs[4096,512] @ fc_w[512,32] + fc_b
// ---------------------------------------------------------------------------
__global__ __launch_bounds__(512) void final_kernel(
    const float* __restrict__ hs, const float* __restrict__ fc_w,
    const float* __restrict__ fc_b, float* __restrict__ out)
{
  const int a = threadIdx.x & 31, r = threadIdx.x >> 5;   // 16 rows/block
  const int row = blockIdx.x * 16 + r;
  const float* h = hs + (size_t)row*512;
  float acc = fc_b[a];
  #pragma unroll 8
  for (int k = 0; k < 512; ++k) acc += h[k] * fc_w[k*32 + a];
  out[(size_t)row*32 + a] = acc;
}

// ---------------------------------------------------------------------------
extern "C" void kernel_launch(void* const* d_in, const int* in_sizes, int n_in,
                              void* d_out, int out_size, void* d_ws, size_t ws_size,
                              hipStream_t stream)
{
  const float* x      = (const float*)d_in[0];
  const int*   length = (const int*)  d_in[1];
  const float* u_nois = (const float*)d_in[2];
  const float* W_ih   = (const float*)d_in[3];
  const float* W_hh   = (const float*)d_in[4];
  const float* bias   = (const float*)d_in[5];
  const float* W_im   = (const float*)d_in[6];
  const float* W_hm   = (const float*)d_in[7];
  const float* W_um   = (const float*)d_in[8];
  const float* fc1_w  = (const float*)d_in[9];
  const float* fc1_b  = (const float*)d_in[10];
  const float* fc2_w  = (const float*)d_in[11];
  const float* fc2_b  = (const float*)d_in[12];
  const float* fc_w   = (const float*)d_in[13];
  const float* fc_b   = (const float*)d_in[14];
  float* out = (float*)d_out;

  float* ws   = (float*)d_ws;
  int*   bar  = (int*)d_ws;
  float* hTx  = ws + OFF_HTX;
  float* hnew = ws + OFF_HNEW;
  float* whh  = ws + OFF_WHH;
  float* usage= ws + OFF_USAGE;
  int*   jst  = (int*)(ws + OFF_JSTAR);
  float* c0   = ws + OFF_C0;
  float* Wcat = ws + OFF_WCAT;
  float* part = ws + OFF_PART;
  float* P1   = ws + OFF_P1;
  float* P2   = ws + OFF_P2;
  float* hsb  = ws + OFF_HS;

  // zero: barrier + hTx (h=0, lu=sigmoid(-99999)=0) + slot caches (mem=0)
  hipMemsetAsync(d_ws, 0, (size_t)OFF_USAGE * sizeof(float), stream);

  setup_kernel<<<2120, 512, 0, stream>>>(W_hm, fc2_w, W_um, W_hh, bias, fc2_b,
                                         Wcat, usage, c0, jst);

  // M_A = fc2_A@W_hh -> Wcat cols 1536:3072 ; M_B = fc2_B@W_hh -> 3072:4608
  { dim3 g(4, 24);
    gemm_f32<<<g, 256, 0, stream>>>(fc2_w,           W_hh, nullptr, Wcat + 1536,
                                    512, 1536, 512, 512, 1536, 4608);
    gemm_f32<<<g, 256, 0, stream>>>(fc2_w + 512*512, W_hh, nullptr, Wcat + 3072,
                                    512, 1536, 512, 512, 1536, 4608); }
  // P1 = x@W_ih + bias_ih ; P2 = x@W_im
  { dim3 g(32, 24);
    gemm_f32<<<g, 256, 0, stream>>>(x, W_ih, bias, P1, 4096, 1536, 512, 512, 1536, 1536); }
  { dim3 g(32, 8);
    gemm_f32<<<g, 256, 0, stream>>>(x, W_im, nullptr, P2, 4096, 512, 512, 512, 512, 512); }

  persist_kernel<<<GRID_P, NTHR, 0, stream>>>(P1, P2, Wcat, part, hTx, hnew, whh,
                                              usage, jst, c0, fc1_w, fc1_b, fc2_b,
                                              u_nois, length, hsb, bar);

  final_kernel<<<256, 512, 0, stream>>>(hsb, fc_w, fc_b, out);
}

// Round 2
// 8278.889 us; speedup vs baseline: 1.1300x; 1.1300x over previous
//
#include <hip/hip_runtime.h>
#include <hip/hip_bf16.h>
#include <math.h>

// Problem constants: T=128, B=32, D=512, H=512, N=64, A=32, TAU=1
#define NTHR 512
#define GRID_P 216          // persistent grid: 18 col-groups x 12 K-splits

// ---- workspace layout (float offsets). Barrier ints live in first 128B. ----
#define OFF_HTX   64                         // hTx: [576][32] = [h rows | lu rows]
#define SZ_HTX    (576*32)
#define OFF_HNEW  (OFF_HTX + SZ_HTX)         // hnew_part: [32][64][512]  (mem slot -> h@fc2_A)
#define SZ_HNEW   (32*64*512)
#define OFF_WHH   (OFF_HNEW + SZ_HNEW)       // whh_part: [32][64][1536] ((h@fc2_A)@W_hh)
#define SZ_WHH    (32*64*1536)
#define OFF_USAGE (OFF_WHH + SZ_WHH)         // usage: [32][64]
#define OFF_JSTAR (OFF_USAGE + 2048)         // jstar: 32 ints
#define OFF_C0    (OFF_JSTAR + 32)           // c0 = fc2_b@W_hh + bias_hh : [1536]
#define OFF_WCAT  (OFF_C0 + 1536)            // Wcat: [576][4608]
#define SZ_WCAT   (576*4608)
#define OFF_PART  (OFF_WCAT + SZ_WCAT)       // split-K partials: [12][32][4608]
#define SZ_PART   (12*32*4608)
#define OFF_P1    (OFF_PART + SZ_PART)       // P1 = x@W_ih + bias_ih : [4096][1536]
#define SZ_P1     (4096*1536)
#define OFF_P2    (OFF_P1 + SZ_P1)           // P2 = x@W_im : [4096][512]
#define SZ_P2     (4096*512)
#define OFF_HS    (OFF_P2 + SZ_P2)           // hs: [4096][512]
// total = OFF_HS + 4096*512 floats ~ 76.5 MB

// ---------------------------------------------------------------------------
// Cross-XCD coherent access WITHOUT cache-wide fences: agent-scope relaxed
// atomics compile to global_load/store with sc1 (bypass per-XCD L2, operate
// at the coherent LLC). Read-only weights keep normal loads -> stay in L2.
// ---------------------------------------------------------------------------
__device__ __forceinline__ float cohLoad(const float* p) {
  return __hip_atomic_load(p, __ATOMIC_RELAXED, __HIP_MEMORY_SCOPE_AGENT);
}
__device__ __forceinline__ void cohStore(float* p, float v) {
  __hip_atomic_store(p, v, __ATOMIC_RELAXED, __HIP_MEMORY_SCOPE_AGENT);
}

// Monotonic relaxed barrier halves. __syncthreads() drains each wave's
// vmcnt before s_barrier, so all sc1 stores are globally visible before
// thread 0 bumps the counter. No threadfence -> no L2 invalidate/writeback.
__device__ __forceinline__ void bar_arrive(int* cnt) {
  __syncthreads();
  if (threadIdx.x == 0)
    __hip_atomic_fetch_add(cnt, 1, __ATOMIC_RELAXED, __HIP_MEMORY_SCOPE_AGENT);
}
__device__ __forceinline__ void bar_wait(int* cnt, int target) {
  if (threadIdx.x == 0) {
    while (__hip_atomic_load(cnt, __ATOMIC_RELAXED, __HIP_MEMORY_SCOPE_AGENT) < target)
      __builtin_amdgcn_s_sleep(1);
  }
  __syncthreads();
}

// ---------------------------------------------------------------------------
// Generic tiled fp32 GEMM: C[M,N] = A[M,K]@B[K,N] (+bias). BM=128 BN=64 BK=16
// ---------------------------------------------------------------------------
__global__ __launch_bounds__(256) void gemm_f32(
    const float* __restrict__ A, const float* __restrict__ B,
    const float* __restrict__ bias, float* __restrict__ C,
    int M, int N, int K, int lda, int ldb, int ldc)
{
  __shared__ float As[16][132];   // [k][m], padded
  __shared__ float Bs[16][64];    // [k][n]
  const int bm = blockIdx.x * 128, bn = blockIdx.y * 64;
  const int tid = threadIdx.x;
  const int tx = tid & 15, ty = tid >> 4;
  float acc[8][4];
  #pragma unroll
  for (int i = 0; i < 8; ++i)
    #pragma unroll
    for (int j = 0; j < 4; ++j) acc[i][j] = 0.f;

  for (int kt = 0; kt < K; kt += 16) {
    #pragma unroll
    for (int i = 0; i < 2; ++i) {
      int li = tid + i*256;
      int r = li >> 2, q = li & 3;
      float4 a4 = *(const float4*)(A + (size_t)(bm + r)*lda + kt + q*4);
      As[q*4+0][r] = a4.x; As[q*4+1][r] = a4.y;
      As[q*4+2][r] = a4.z; As[q*4+3][r] = a4.w;
    }
    {
      int k = tid >> 4, nq = tid & 15;
      *(float4*)(&Bs[k][nq*4]) = *(const float4*)(B + (size_t)(kt + k)*ldb + bn + nq*4);
    }
    __syncthreads();
    #pragma unroll
    for (int kk = 0; kk < 16; ++kk) {
      float av[8], bv[4];
      *(float4*)(av)   = *(const float4*)(&As[kk][ty*8]);
      *(float4*)(av+4) = *(const float4*)(&As[kk][ty*8+4]);
      *(float4*)(bv)   = *(const float4*)(&Bs[kk][tx*4]);
      #pragma unroll
      for (int i = 0; i < 8; ++i)
        #pragma unroll
        for (int j = 0; j < 4; ++j) acc[i][j] += av[i]*bv[j];
    }
    __syncthreads();
  }
  #pragma unroll
  for (int i = 0; i < 8; ++i) {
    int m = bm + ty*8 + i;
    #pragma unroll
    for (int j = 0; j < 4; ++j) {
      int n = bn + tx*4 + j;
      float v = acc[i][j];
      if (bias) v += bias[n];
      C[(size_t)m*ldc + n] = v;
    }
  }
}

// ---------------------------------------------------------------------------
// Setup: build Wcat static parts, usage init, c0, jstar.
// ---------------------------------------------------------------------------
__global__ __launch_bounds__(512) void setup_kernel(
    const float* __restrict__ W_hm, const float* __restrict__ fc2_w,
    const float* __restrict__ W_um, const float* __restrict__ W_hh,
    const float* __restrict__ bias, const float* __restrict__ fc2_b,
    float* __restrict__ Wcat, float* __restrict__ usage,
    float* __restrict__ c0, int* __restrict__ jstar)
{
  const int idx = blockIdx.x * 512 + threadIdx.x;
  if (idx < 512*1536) {                       // seg0: rows 0:512, cols 0:1536
    int k = idx / 1536, c = idx % 1536;
    float v;
    if (c < 512)       v = W_hm[k*512 + c];
    else if (c < 1024) v = fc2_w[k*512 + (c-512)];
    else               v = fc2_w[(512+k)*512 + (c-1024)];
    Wcat[(size_t)k*4608 + c] = v;
    return;
  }
  int i = idx - 512*1536;
  if (i < 64*4608) {                          // seg1: rows 512:576, all cols
    int k2 = i / 4608, c = i % 4608;
    Wcat[(size_t)(512+k2)*4608 + c] = (c < 512) ? W_um[k2*512 + c] : 0.f;
    return;
  }
  i -= 64*4608;
  if (i < 2048) { usage[i] = -99999.0f; return; }
  i -= 2048;
  if (i < 32) { jstar[i] = 0; return; }
  i -= 32;
  if (i < 1536) {                             // c0 = fc2_b@W_hh + bias_hh
    float s = bias[1536 + i];
    for (int m = 0; m < 512; ++m) s += fc2_b[m] * W_hh[m*1536 + i];
    c0[i] = s;
  }
}

// ---------------------------------------------------------------------------
// Persistent scan kernel. Per step: Phase A (split-K GEMM, all 216 blocks),
// asymmetric barrier, Phase BC (argmax + elementwise, 32 blocks), barrier.
// Cross-block data (hTx, partial) via sc1 atomics; weights stay in L2.
// ---------------------------------------------------------------------------
__global__ __launch_bounds__(NTHR, 2) void persist_kernel(
    const float* __restrict__ P1, const float* __restrict__ P2,
    const float* __restrict__ Wcat, float* __restrict__ partial,
    float* __restrict__ hTx, float* __restrict__ hnew_part,
    float* __restrict__ whh_part, float* __restrict__ usage,
    int* __restrict__ jstar, const float* __restrict__ c0,
    const float* __restrict__ fc1_w, const float* __restrict__ fc1_b,
    const float* __restrict__ fc2_b, const float* __restrict__ u_noise,
    const int* __restrict__ length, float* __restrict__ hs,
    int* __restrict__ bar)
{
  __shared__ float hxs[48*32];     // staged hx rows for this K-split
  __shared__ float red[32*256];    // K-half reduction
  __shared__ float th_s[512];
  __shared__ float lg[512];
  __shared__ float lsc[64];
  __shared__ int jj_s, ss_s;

  const int bid = blockIdx.x;
  const int tid = threadIdx.x;
  int* cnt1 = bar;                 // phase-A arrivals (all 216 blocks)
  int* cnt2 = bar + 32;            // phase-BC arrivals (32 blocks), own line

  const int cg = bid / 12;          // 0..17: 256-column group
  const int ks = bid % 12;          // 0..11: 48-row K split
  const int c  = tid & 255;
  const int kh = tid >> 8;          // K half (24 rows each)
  const int col = cg*256 + c;

  for (int t = 0; t < 128; ++t) {
    // ---------------- PHASE A: partial[ks] = hx[ksplit] @ Wcat[:, col] -----
    for (int i = tid; i < 48*32; i += NTHR) hxs[i] = cohLoad(&hTx[ks*48*32 + i]);
    __syncthreads();
    {
      float acc[32];
      #pragma unroll
      for (int b = 0; b < 32; ++b) acc[b] = 0.f;
      const float* wp = Wcat + (size_t)(ks*48 + kh*24)*4608 + col;
      const float* hb = hxs + kh*24*32;
      float w = wp[0];
      for (int k = 0; k < 24; ++k) {
        float wn = (k < 23) ? wp[(size_t)(k+1)*4608] : 0.f;
        const float* h4p = hb + k*32;
        #pragma unroll
        for (int q = 0; q < 8; ++q) {
          float4 h4 = *(const float4*)(h4p + q*4);
          acc[q*4+0] += w*h4.x; acc[q*4+1] += w*h4.y;
          acc[q*4+2] += w*h4.z; acc[q*4+3] += w*h4.w;
        }
        w = wn;
      }
      if (kh == 1) {
        #pragma unroll
        for (int b = 0; b < 32; ++b) red[b*256 + c] = acc[b];
      }
      __syncthreads();
      if (kh == 0) {
        float* pp = partial + (size_t)(ks*32)*4608 + col;
        #pragma unroll
        for (int b = 0; b < 32; ++b) cohStore(&pp[(size_t)b*4608], acc[b] + red[b*256 + c]);
      }
    }
    bar_arrive(cnt1);                          // all 216 arrive

    // ---------------- PHASE BC: block b<32 handles batch b -----------------
    if (bid < 32) {
      bar_wait(cnt1, (t + 1) * GRID_P);        // only BC blocks wait here
      const int b = bid;
      const int t32b = t*32 + b;
      // th = tanh(P2 + sum_s partial[:, 0:512])
      {
        float pre = P2[(size_t)t32b*512 + tid];
        #pragma unroll
        for (int s = 0; s < 12; ++s) pre += cohLoad(&partial[(size_t)(s*32+b)*4608 + tid]);
        th_s[tid] = tanhf(pre);
      }
      __syncthreads();
      // logits partial dots
      {
        int n = tid & 63, kg = tid >> 6;
        float sum = 0.f;
        const float* fw = fc1_w + (size_t)kg*64*64 + n;
        #pragma unroll 8
        for (int k = 0; k < 64; ++k) sum += th_s[kg*64 + k] * fw[(size_t)k*64];
        lg[tid] = sum;
      }
      __syncthreads();
      if (tid < 64) {
        float l = fc1_b[tid];
        #pragma unroll
        for (int kg = 0; kg < 8; ++kg) l += lg[kg*64 + tid];
        float u = u_noise[(size_t)t32b*64 + tid];
        l += -logf(1e-20f - logf(1e-20f + u));     // Gumbel
        lsc[tid] = l;
      }
      __syncthreads();
      if (tid == 0) {
        int jj = 0; float best = lsc[0];
        for (int n2 = 1; n2 < 64; ++n2)
          if (lsc[n2] > best) { best = lsc[n2]; jj = n2; }   // first-max wins
        jj_s = jj;
        ss_s = (t < 64) ? t : jstar[b];   // write slot (mem write precedes read)
        jstar[b] = jj;
      }
      __syncthreads();
      const int jj = jj_s, ss = ss_s;
      {
        const int j = tid;    // 0..511
        float vA=0.f, vB=0.f, vAW0=0.f, vAW1=0.f, vAW2=0.f, vBW0=0.f, vBW1=0.f, vBW2=0.f;
        #pragma unroll
        for (int s = 0; s < 12; ++s) {
          const float* pr = partial + (size_t)(s*32+b)*4608;
          vA   += cohLoad(&pr[ 512 + j]); vB   += cohLoad(&pr[1024 + j]);
          vAW0 += cohLoad(&pr[1536 + j]); vAW1 += cohLoad(&pr[2048 + j]); vAW2 += cohLoad(&pr[2560 + j]);
          vBW0 += cohLoad(&pr[3072 + j]); vBW1 += cohLoad(&pr[3584 + j]); vBW2 += cohLoad(&pr[4096 + j]);
        }
        float hnp, w0, w1, w2;
        if (jj == ss) { hnp = vA; w0 = vAW0; w1 = vAW1; w2 = vAW2; }  // reads just-written slot
        else {
          hnp = hnew_part[(size_t)(b*64 + jj)*512 + j];
          const float* wpp = whh_part + (size_t)(b*64 + jj)*1536;
          w0 = wpp[j]; w1 = wpp[512 + j]; w2 = wpp[1024 + j];
        }
        float h_new = hnp + vB + fc2_b[j];
        float wh_r = w0 + vBW0 + c0[j];
        float wh_z = w1 + vBW1 + c0[512 + j];
        float wh_n = w2 + vBW2 + c0[1024 + j];
        const float* p1 = P1 + (size_t)t32b*1536;
        float r = 1.f / (1.f + expf(-(p1[j]        + wh_r)));
        float z = 1.f / (1.f + expf(-(p1[512 + j]  + wh_z)));
        float nn = tanhf(p1[1024 + j] + r*wh_n);
        float h1 = (1.f - z)*nn + z*h_new;
        float hprev = cohLoad(&hTx[j*32 + b]);
        if (t >= length[b]) h1 = hprev;                    // length mask
        cohStore(&hTx[j*32 + b], h1);
        hs[(size_t)t32b*512 + j] = h1;
        hnew_part[(size_t)(b*64 + ss)*512 + j] = vA;       // mem slot write cache
        float* wps = whh_part + (size_t)(b*64 + ss)*1536;
        wps[j] = vAW0; wps[512 + j] = vAW1; wps[1024 + j] = vAW2;
      }
      if (tid < 64) {
        float un = (usage[b*64 + tid] - 1.f) * (tid == jj_s ? 0.f : 1.f);
        usage[b*64 + tid] = un;
        cohStore(&hTx[(512 + tid)*32 + b], 1.f / (1.f + expf(-un))); // lu
      }
      bar_arrive(cnt2);                        // only 32 BC blocks arrive
    }
    bar_wait(cnt2, (t + 1) * 32);              // everyone waits for BC done
  }
}

// ---------------------------------------------------------------------------
// out[4096,32] = hs[4096,512] @ fc_w[512,32] + fc_b
// ---------------------------------------------------------------------------
__global__ __launch_bounds__(512) void final_kernel(
    const float* __restrict__ hs, const float* __restrict__ fc_w,
    const float* __restrict__ fc_b, float* __restrict__ out)
{
  const int a = threadIdx.x & 31, r = threadIdx.x >> 5;   // 16 rows/block
  const int row = blockIdx.x * 16 + r;
  const float* h = hs + (size_t)row*512;
  float acc = fc_b[a];
  #pragma unroll 8
  for (int k = 0; k < 512; ++k) acc += h[k] * fc_w[k*32 + a];
  out[(size_t)row*32 + a] = acc;
}

// ---------------------------------------------------------------------------
extern "C" void kernel_launch(void* const* d_in, const int* in_sizes, int n_in,
                              void* d_out, int out_size, void* d_ws, size_t ws_size,
                              hipStream_t stream)
{
  const float* x      = (const float*)d_in[0];
  const int*   length = (const int*)  d_in[1];
  const float* u_nois = (const float*)d_in[2];
  const float* W_ih   = (const float*)d_in[3];
  const float* W_hh   = (const float*)d_in[4];
  const float* bias   = (const float*)d_in[5];
  const float* W_im   = (const float*)d_in[6];
  const float* W_hm   = (const float*)d_in[7];
  const float* W_um   = (const float*)d_in[8];
  const float* fc1_w  = (const float*)d_in[9];
  const float* fc1_b  = (const float*)d_in[10];
  const float* fc2_w  = (const float*)d_in[11];
  const float* fc2_b  = (const float*)d_in[12];
  const float* fc_w   = (const float*)d_in[13];
  const float* fc_b   = (const float*)d_in[14];
  float* out = (float*)d_out;

  float* ws   = (float*)d_ws;
  int*   bar  = (int*)d_ws;
  float* hTx  = ws + OFF_HTX;
  float* hnew = ws + OFF_HNEW;
  float* whh  = ws + OFF_WHH;
  float* usage= ws + OFF_USAGE;
  int*   jst  = (int*)(ws + OFF_JSTAR);
  float* c0   = ws + OFF_C0;
  float* Wcat = ws + OFF_WCAT;
  float* part = ws + OFF_PART;
  float* P1   = ws + OFF_P1;
  float* P2   = ws + OFF_P2;
  float* hsb  = ws + OFF_HS;

  // zero: barrier counters + hTx (h=0, lu=0) + slot caches (mem=0)
  hipMemsetAsync(d_ws, 0, (size_t)OFF_USAGE * sizeof(float), stream);

  setup_kernel<<<2120, 512, 0, stream>>>(W_hm, fc2_w, W_um, W_hh, bias, fc2_b,
                                         Wcat, usage, c0, jst);

  // M_A = fc2_A@W_hh -> Wcat cols 1536:3072 ; M_B = fc2_B@W_hh -> 3072:4608
  { dim3 g(4, 24);
    gemm_f32<<<g, 256, 0, stream>>>(fc2_w,           W_hh, nullptr, Wcat + 1536,
                                    512, 1536, 512, 512, 1536, 4608);
    gemm_f32<<<g, 256, 0, stream>>>(fc2_w + 512*512, W_hh, nullptr, Wcat + 3072,
                                    512, 1536, 512, 512, 1536, 4608); }
  // P1 = x@W_ih + bias_ih ; P2 = x@W_im
  { dim3 g(32, 24);
    gemm_f32<<<g, 256, 0, stream>>>(x, W_ih, bias, P1, 4096, 1536, 512, 512, 1536, 1536); }
  { dim3 g(32, 8);
    gemm_f32<<<g, 256, 0, stream>>>(x, W_im, nullptr, P2, 4096, 512, 512, 512, 512, 512); }

  persist_kernel<<<GRID_P, NTHR, 0, stream>>>(P1, P2, Wcat, part, hTx, hnew, whh,
                                              usage, jst, c0, fc1_w, fc1_b, fc2_b,
                                              u_nois, length, hsb, bar);

  final_kernel<<<256, 512, 0, stream>>>(hsb, fc_w, fc_b, out);
}